// Round 3
// baseline (5202.891 us; speedup 1.0000x reference)
//
#include <hip/hip_runtime.h>

#define EPS 1e-12f

// Scratch layout in d_ws (floats):
//   upA: [1024][15][16]  (padded u, col 15 is zero pad)   = 245760
//   upB: [1024][15][16]                                   = 245760
//   sig: [1024]
// Padded relation: up[c][py][px] = u[c][(py+9)%11][(px+9)%11], py,px in 0..14

__global__ __launch_bounds__(128) void norm0_kernel(const float* __restrict__ u0,
                                                    float* __restrict__ up)
{
    __shared__ float u_l[121];
    __shared__ float tmp[2];
    int c = blockIdx.x;
    int t = threadIdx.x;
    float v = 0.f;
    if (t < 121) v = u0[c * 121 + t];
    float ss = v * v;
    #pragma unroll
    for (int m = 32; m >= 1; m >>= 1) ss += __shfl_xor(ss, m, 64);
    if ((t & 63) == 0) tmp[t >> 6] = ss;
    __syncthreads();
    float total = tmp[0] + tmp[1];
    float inv = 1.f / (sqrtf(total) + EPS);
    if (t < 121) u_l[t] = v * inv;
    __syncthreads();
    for (int idx = t; idx < 240; idx += 128) {
        int py = idx >> 4, px = idx & 15;
        float w = 0.f;
        if (px < 15) {
            int y = (py + 9) % 11;
            int x = (px + 9) % 11;
            w = u_l[y * 11 + x];
        }
        up[c * 240 + idx] = w;
    }
}

// Per-half conv body. Thread = (lane_ci in 0..127) x (spatial half).
// Y_LO..Y_HI: output rows owned. Accumulates over ci = lane_ci + 128k,
// butterfly-reduces over the 64 lanes, then combines the half's two waves
// into red[] (one lane per slot, predicated static loop -> no dynamic
// register indexing).
template<int Y_LO, int Y_HI>
__device__ __forceinline__ void conv_part(const float* __restrict__ W,
        const float* __restrict__ upi, int co, int lane_ci,
        float* __restrict__ red)
{
    constexpr int NOUT = (Y_HI - Y_LO + 1) * 11;
    constexpr int OB = Y_LO * 11;
    int lane = lane_ci & 63;

    float acc[NOUT];
    #pragma unroll
    for (int i = 0; i < NOUT; ++i) acc[i] = 0.f;

    for (int k = 0; k < 8; ++k) {
        int ci = lane_ci + (k << 7);
        const float* wp = W + ((size_t)co * 1024 + (size_t)ci) * 25;
        float wr[25];
        #pragma unroll
        for (int i = 0; i < 25; ++i) wr[i] = wp[i];
        const float4* rb = (const float4*)(upi + ci * 240);
        #pragma unroll
        for (int r = Y_LO; r <= Y_HI + 4; ++r) {
            float4 q0 = rb[r * 4 + 0];
            float4 q1 = rb[r * 4 + 1];
            float4 q2 = rb[r * 4 + 2];
            float4 q3 = rb[r * 4 + 3];
            float row[16] = {q0.x, q0.y, q0.z, q0.w, q1.x, q1.y, q1.z, q1.w,
                             q2.x, q2.y, q2.z, q2.w, q3.x, q3.y, q3.z, q3.w};
            #pragma unroll
            for (int ky = 0; ky < 5; ++ky) {
                int y = r - ky;                       // static after unroll
                if (y < Y_LO || y > Y_HI) continue;
                #pragma unroll
                for (int kx = 0; kx < 5; ++kx) {
                    float wv = wr[ky * 5 + kx];
                    #pragma unroll
                    for (int x = 0; x < 11; ++x)
                        acc[(y - Y_LO) * 11 + x] =
                            fmaf(row[x + kx], wv, acc[(y - Y_LO) * 11 + x]);
                }
            }
        }
    }

    // 64-lane butterfly: every lane ends with the wave-sum of each output.
    #pragma unroll
    for (int i = 0; i < NOUT; ++i) {
        float s = acc[i];
        #pragma unroll
        for (int m = 32; m >= 1; m >>= 1) s += __shfl_xor(s, m, 64);
        acc[i] = s;
    }

    // Cross-wave combine (the half's two ci-waves), one lane per slot.
    if (lane_ci >= 64) {
        #pragma unroll
        for (int i = 0; i < NOUT; ++i)
            if ((i & 63) == lane) red[OB + i] = acc[i];
    }
    __syncthreads();   // executed once by every wave (uniform per wave)
    if (lane_ci < 64) {
        #pragma unroll
        for (int i = 0; i < NOUT; ++i)
            if ((i & 63) == lane) red[OB + i] += acc[i];
    }
}

// One block per co: 256 threads = 128 ci-lanes x 2 spatial halves.
// __launch_bounds__(256,4): VGPR cap 128 -> 4 waves/SIMD, 4 blocks/CU.
__global__ __launch_bounds__(256, 4) void conv_kernel(const float* __restrict__ W,
        const float* __restrict__ upi, float* __restrict__ upo,
        float* __restrict__ sigmas, int write_sigma)
{
    __shared__ float red[128];
    __shared__ float u_l[121];
    int co = blockIdx.x;
    int t = threadIdx.x;
    int lane_ci = t & 127;
    int half = t >> 7;

    if (half == 0) conv_part<0, 5>(W, upi, co, lane_ci, red);
    else           conv_part<6, 10>(W, upi, co, lane_ci, red);
    __syncthreads();

    // ---- fused epilogue: norm, sigma, normalize, circular-pad write ----
    if (t < 64) {
        float v1 = red[t];
        float v2 = (t < 57) ? red[64 + t] : 0.f;
        float ss = v1 * v1 + v2 * v2;
        #pragma unroll
        for (int m = 32; m >= 1; m >>= 1) ss += __shfl_xor(ss, m, 64);
        float norm = sqrtf(ss);
        float inv = 1.f / (norm + EPS);
        u_l[t] = v1 * inv;
        if (t < 57) u_l[64 + t] = v2 * inv;
        if (t == 0 && write_sigma) sigmas[co] = norm;
    }
    __syncthreads();
    for (int idx = t; idx < 240; idx += 256) {
        int py = idx >> 4, px = idx & 15;
        float w = 0.f;
        if (px < 15) {
            int y = (py + 9) % 11;
            int x = (px + 9) % 11;
            w = u_l[y * 11 + x];
        }
        upo[co * 240 + idx] = w;
    }
}

__global__ __launch_bounds__(256) void scale_kernel(const float* __restrict__ W,
        const float* __restrict__ sigmas, float* __restrict__ out)
{
    int co = blockIdx.x;
    float inv = 1.f / sigmas[co];     // one precise divide; then multiply
    const float4* src = (const float4*)(W + (size_t)co * 25600);
    float4* dst = (float4*)(out + (size_t)co * 25600);
    for (int i = threadIdx.x; i < 6400; i += 256) {
        float4 v = src[i];
        v.x *= inv; v.y *= inv; v.z *= inv; v.w *= inv;
        dst[i] = v;
    }
}

extern "C" void kernel_launch(void* const* d_in, const int* in_sizes, int n_in,
                              void* d_out, int out_size, void* d_ws, size_t ws_size,
                              hipStream_t stream)
{
    const float* W  = (const float*)d_in[0];   // (1024,1024,5,5)
    const float* u0 = (const float*)d_in[1];   // (1,1024,11,11)
    float* out = (float*)d_out;                // (1024,1024,5,5)

    float* upA = (float*)d_ws;
    float* upB = upA + 1024 * 240;
    float* sig = upB + 1024 * 240;

    hipLaunchKernelGGL(norm0_kernel, dim3(1024), dim3(128), 0, stream, u0, upA);
    hipLaunchKernelGGL(conv_kernel,  dim3(1024), dim3(256), 0, stream, W, upA, upB, sig, 0);
    hipLaunchKernelGGL(conv_kernel,  dim3(1024), dim3(256), 0, stream, W, upB, upA, sig, 0);
    hipLaunchKernelGGL(conv_kernel,  dim3(1024), dim3(256), 0, stream, W, upA, upB, sig, 1);
    hipLaunchKernelGGL(scale_kernel, dim3(1024), dim3(256), 0, stream, W, sig, out);
}

// Round 5
// 1621.614 us; speedup vs baseline: 3.2085x; 3.2085x over previous
//
#include <hip/hip_runtime.h>

#define EPS 1e-12f

// Scratch layout in d_ws (floats):
//   upA: [225][1024]  channel-last padded u  (p = py*15+px, py,px in 0..14)
//   upB: [225][1024]
//   sig: [1024]
//   Wt : [1024][25][1024]  transposed kernel (only if ws_size permits)
// Padded relation: upT[py*15+px][c] = u[c][(py+9)%11][(px+9)%11]

__global__ __launch_bounds__(128) void norm0_kernel(const float* __restrict__ u0,
                                                    float* __restrict__ up)
{
    __shared__ float u_l[121];
    __shared__ float tmp[2];
    int c = blockIdx.x;
    int t = threadIdx.x;
    float v = 0.f;
    if (t < 121) v = u0[c * 121 + t];
    float ss = v * v;
    #pragma unroll
    for (int m = 32; m >= 1; m >>= 1) ss += __shfl_xor(ss, m, 64);
    if ((t & 63) == 0) tmp[t >> 6] = ss;
    __syncthreads();
    float total = tmp[0] + tmp[1];
    float inv = 1.f / (sqrtf(total) + EPS);
    if (t < 121) u_l[t] = v * inv;
    __syncthreads();
    for (int idx = t; idx < 225; idx += 128) {
        int py = idx / 15, px = idx % 15;
        int y = (py + 9) % 11;
        int x = (px + 9) % 11;
        up[idx * 1024 + c] = u_l[y * 11 + x];
    }
}

// W[co][ci][tap] -> Wt[co][tap][ci], LDS-staged so both sides are coalesced.
__global__ __launch_bounds__(256) void transw_kernel(const float* __restrict__ W,
                                                     float* __restrict__ Wt)
{
    __shared__ float ld[256][27];   // pad 27: odd stride -> conflict-free col read
    int co = blockIdx.x;
    int cib = blockIdx.y << 8;      // ci chunk base (0,256,512,768)
    int t = threadIdx.x;
    const float* src = W + (size_t)co * 25600 + (size_t)cib * 25;
    #pragma unroll
    for (int j = 0; j < 25; ++j) {
        int f = j * 256 + t;        // 0..6399 contiguous
        ld[f / 25][f % 25] = src[f];
    }
    __syncthreads();
    float* dst = Wt + (size_t)co * 25600 + cib;
    #pragma unroll
    for (int j = 0; j < 25; ++j)
        dst[j * 1024 + t] = ld[t][j];
}

// One row-group's conv work. lane_ci in 0..127 selects ci = lane_ci+128k.
// All loads lane-coalesced (consecutive ci). Butterfly-reduce over the wave,
// then 2-wave combine into red[] (one lane per output slot; NOUT<=33<64).
template<int Y_LO, int Y_HI>
__device__ __forceinline__ void conv_group(
        const float* __restrict__ Wco, int st_tap, int st_ci,
        const float* __restrict__ upi, int lane_ci, float* __restrict__ red)
{
    constexpr int NROW = Y_HI - Y_LO + 1;
    constexpr int NOUT = NROW * 11;
    constexpr int OB = Y_LO * 11;
    const int lane = lane_ci & 63;

    float acc[NOUT];
    #pragma unroll
    for (int i = 0; i < NOUT; ++i) acc[i] = 0.f;

    for (int k = 0; k < 8; ++k) {
        const int ci = lane_ci + (k << 7);
        float wr[25];
        #pragma unroll
        for (int i = 0; i < 25; ++i) wr[i] = Wco[i * st_tap + ci * st_ci];
        #pragma unroll
        for (int r = Y_LO; r <= Y_HI + 4; ++r) {
            float row[15];
            #pragma unroll
            for (int x = 0; x < 15; ++x) row[x] = upi[(r * 15 + x) * 1024 + ci];
            #pragma unroll
            for (int ky = 0; ky < 5; ++ky) {
                const int y = r - ky;                 // static after unroll
                if (y < Y_LO || y > Y_HI) continue;
                #pragma unroll
                for (int kx = 0; kx < 5; ++kx) {
                    const float wv = wr[ky * 5 + kx];
                    #pragma unroll
                    for (int x = 0; x < 11; ++x)
                        acc[(y - Y_LO) * 11 + x] =
                            fmaf(row[x + kx], wv, acc[(y - Y_LO) * 11 + x]);
                }
            }
        }
    }

    #pragma unroll
    for (int i = 0; i < NOUT; ++i) {
        float s = acc[i];
        #pragma unroll
        for (int m = 32; m >= 1; m >>= 1) s += __shfl_xor(s, m, 64);
        acc[i] = s;
    }
    if (lane_ci >= 64) {
        #pragma unroll
        for (int i = 0; i < NOUT; ++i)
            if (lane == i) red[OB + i] = acc[i];
    }
    __syncthreads();    // executed exactly once by every wave in the block
    if (lane_ci < 64) {
        #pragma unroll
        for (int i = 0; i < NOUT; ++i)
            if (lane == i) red[OB + i] += acc[i];
    }
}

// One block per co: 512 threads = 128 ci-lanes x 4 row-groups (3,3,3,2 rows).
// amdgpu_waves_per_eu(4): VGPR cap 128 (direct attribute; launch_bounds'
// 2nd arg translates 2x too aggressively on this toolchain: (256,4)->64!).
// Per-thread live state ~95 VGPR -> no spill, 4 waves/SIMD.
__global__ __launch_bounds__(512)
__attribute__((amdgpu_waves_per_eu(4)))
void conv_kernel(const float* __restrict__ Wp, int st_tap, int st_ci,
                 const float* __restrict__ upi, float* __restrict__ upo,
                 float* __restrict__ sigmas, int write_sigma)
{
    __shared__ float red[121];
    __shared__ float sh_norm;
    const int co = blockIdx.x;
    const int t = threadIdx.x;
    const int lane_ci = t & 127;
    const int grp = t >> 7;
    const float* Wco = Wp + (size_t)co * 25600;

    switch (grp) {
        case 0:  conv_group<0, 2>(Wco, st_tap, st_ci, upi, lane_ci, red); break;
        case 1:  conv_group<3, 5>(Wco, st_tap, st_ci, upi, lane_ci, red); break;
        case 2:  conv_group<6, 8>(Wco, st_tap, st_ci, upi, lane_ci, red); break;
        default: conv_group<9, 10>(Wco, st_tap, st_ci, upi, lane_ci, red); break;
    }
    __syncthreads();

    if (t < 64) {
        float v1 = red[t];
        float v2 = (t < 57) ? red[64 + t] : 0.f;
        float ss = v1 * v1 + v2 * v2;
        #pragma unroll
        for (int m = 32; m >= 1; m >>= 1) ss += __shfl_xor(ss, m, 64);
        if (t == 0) {
            float nrm = sqrtf(ss);
            sh_norm = nrm;
            if (write_sigma) sigmas[co] = nrm;
        }
    }
    __syncthreads();
    const float inv = 1.f / (sh_norm + EPS);
    if (t < 225) {
        int py = t / 15, px = t % 15;
        int y = (py + 9) % 11;
        int x = (px + 9) % 11;
        upo[t * 1024 + co] = red[y * 11 + x] * inv;
    }
}

__global__ __launch_bounds__(256) void scale_kernel(const float* __restrict__ W,
        const float* __restrict__ sigmas, float* __restrict__ out)
{
    int co = blockIdx.x;
    float inv = 1.f / sigmas[co];     // one precise divide; then multiply
    const float4* src = (const float4*)(W + (size_t)co * 25600);
    float4* dst = (float4*)(out + (size_t)co * 25600);
    for (int i = threadIdx.x; i < 6400; i += 256) {
        float4 v = src[i];
        v.x *= inv; v.y *= inv; v.z *= inv; v.w *= inv;
        dst[i] = v;
    }
}

extern "C" void kernel_launch(void* const* d_in, const int* in_sizes, int n_in,
                              void* d_out, int out_size, void* d_ws, size_t ws_size,
                              hipStream_t stream)
{
    const float* W  = (const float*)d_in[0];   // (1024,1024,5,5)
    const float* u0 = (const float*)d_in[1];   // (1,1024,11,11)
    float* out = (float*)d_out;                // (1024,1024,5,5)

    float* upA = (float*)d_ws;
    float* upB = upA + 225 * 1024;
    float* sig = upB + 225 * 1024;
    float* Wt  = sig + 1024;

    const size_t need = ((size_t)225 * 1024 * 2 + 1024 + (size_t)25600 * 1024) * 4;
    const bool use_wt = ws_size >= need;   // deterministic per process: graph-safe

    const float* Wp;
    int st_tap, st_ci;
    if (use_wt) {
        hipLaunchKernelGGL(transw_kernel, dim3(1024, 4), dim3(256), 0, stream, W, Wt);
        Wp = Wt; st_tap = 1024; st_ci = 1;
    } else {
        Wp = W;  st_tap = 1;    st_ci = 25;
    }

    hipLaunchKernelGGL(norm0_kernel, dim3(1024), dim3(128), 0, stream, u0, upA);
    hipLaunchKernelGGL(conv_kernel,  dim3(1024), dim3(512), 0, stream,
                       Wp, st_tap, st_ci, upA, upB, sig, 0);
    hipLaunchKernelGGL(conv_kernel,  dim3(1024), dim3(512), 0, stream,
                       Wp, st_tap, st_ci, upB, upA, sig, 0);
    hipLaunchKernelGGL(conv_kernel,  dim3(1024), dim3(512), 0, stream,
                       Wp, st_tap, st_ci, upA, upB, sig, 1);
    hipLaunchKernelGGL(scale_kernel, dim3(1024), dim3(256), 0, stream, W, sig, out);
}